// Round 9
// baseline (381.549 us; speedup 1.0000x reference)
//
#include <hip/hip_runtime.h>
#include <stdint.h>

// Causal SDPA B=4,H=16,S=2048,D=64 fp32. Flash-MFMA bf16, round 13.
// v8 structure (proven 75us: 1024 blocks x 256thr, pair-blocks (A,31-A),
// head=n&63 => same-XCD L2 streams [validated in r12: FETCH 133->33MB],
// 2-barrier staging, P-LDS x32 PV, cvt_pk pack, scale folded into Q)
// + P-BUFFER XOR-SWIZZLE replacing PADP padding:
//     col8' = col8 ^ ((row&7)<<1)   (8-short granules; even XOR keeps
//     b128 reads 16B-aligned; bijective per row)
//   -> P dense [32][64], LDS 34816 -> 32768 = EXACTLY 5 blocks/CU.
// + __launch_bounds__(256,5): capacity 4->5 blocks/CU so the dispatcher
//   can backfill freed slots (v8's 36% occupancy vs 50% cap = tail waste;
//   v10 law: wall ~ 1/resident-waves).
// v12 post-mortem: 4-tile/512thr shape net-negative (8-wave barrier
// convergence + coarser tail) despite XCD fix -> reverted to v8 shape.

#define SLEN 2048
#define DHEAD 64
#define NHEADS 64
#define NELEM (SLEN * DHEAD * NHEADS)   // 8388608 per tensor

typedef short bf16x8 __attribute__((ext_vector_type(8)));
typedef float f32x4 __attribute__((ext_vector_type(4)));

__device__ __forceinline__ uint32_t pkbf(float hi, float lo) {
    uint32_t a = __builtin_bit_cast(uint32_t, lo) + 0x8000u;
    uint32_t b = __builtin_bit_cast(uint32_t, hi) + 0x8000u;
    return __builtin_amdgcn_perm(b, a, 0x07060302u);
}
__device__ __forceinline__ unsigned short f2bf(float f) {
    return (unsigned short)((__builtin_bit_cast(uint32_t, f) + 0x8000u) >> 16);
}
__device__ __forceinline__ int swz(int row, int g) {  // offset in shorts, 64x64 tile
    return row * 64 + ((g ^ (row & 7)) << 3);
}

// ---------------- pass 1: K straight, V transposed (identical to round 0) ----------------
__global__ __launch_bounds__(256)
void convert_prep(const float* __restrict__ K, const float* __restrict__ V,
                  unsigned short* __restrict__ Kb, unsigned short* __restrict__ Vtb) {
    __shared__ unsigned short Lt[64 * 264];
    const int b = blockIdx.x, t = threadIdx.x;
    if (b < 4096) {
        const int off = (b * 256 + t) * 8;
        float4 a = *(const float4*)(K + off);
        float4 c = *(const float4*)(K + off + 4);
        uint4 o;
        o.x = pkbf(a.y, a.x); o.y = pkbf(a.w, a.z);
        o.z = pkbf(c.y, c.x); o.w = pkbf(c.w, c.z);
        *(uint4*)(Kb + off) = o;
    } else {
        const int vb2 = b - 4096;
        const int head = vb2 >> 3, kblk = vb2 & 7;
        const float* Vh = V + (size_t)head * (SLEN * DHEAD) + kblk * 256 * DHEAD;
        unsigned short* Vo = Vtb + (size_t)head * (SLEN * DHEAD) + kblk * 256;
#pragma unroll
        for (int i = 0; i < 16; ++i) {
            int idx = t + 256 * i;
            int key = idx >> 4, d4 = idx & 15;
            float4 v = *(const float4*)(Vh + key * DHEAD + d4 * 4);
            Lt[(d4 * 4 + 0) * 264 + key] = f2bf(v.x);
            Lt[(d4 * 4 + 1) * 264 + key] = f2bf(v.y);
            Lt[(d4 * 4 + 2) * 264 + key] = f2bf(v.z);
            Lt[(d4 * 4 + 3) * 264 + key] = f2bf(v.w);
        }
        __syncthreads();
#pragma unroll
        for (int jj = 0; jj < 8; ++jj) {
            int idx = t + 256 * jj;
            int d = idx >> 5, k8 = idx & 31;
            *(uint4*)(Vo + (size_t)d * SLEN + k8 * 8) = *(const uint4*)(Lt + d * 264 + k8 * 8);
        }
    }
}

// ---------------- pass 2: flash attention, balanced pair-blocks ----------------
__global__ __launch_bounds__(256, 5)
void sdpa_mfma(const float* __restrict__ Qf, const unsigned short* __restrict__ Kb,
               const unsigned short* __restrict__ Vtb, float* __restrict__ Og) {
    const int n = blockIdx.x;
    const int j = n >> 8, c = n & 255;
    const int head = c & 63;              // head%8 == n%8 -> same-XCD L2 stream
    const int A  = (c >> 6) + 4 * j;   // 0..15
    const int Bq = 31 - A;             // 16..31

    const size_t hb = (size_t)head * SLEN * DHEAD;
    const float* Qh = Qf + hb;
    const unsigned short* Kh  = Kb + hb;
    const unsigned short* Vth = Vtb + hb;   // [d][2048]
    float* Oh = Og + hb;

    const int tid  = threadIdx.x;
    const int w    = tid >> 6, lane = tid & 63;
    const int cl   = lane & 15, quad = lane >> 4;

    __shared__ unsigned short Kl[64 * 64];       //  8192 B swizzled [key][d]
    __shared__ unsigned short Vt[64 * 64];       //  8192 B swizzled [d][key]
    __shared__ unsigned short Pl[4 * 32 * 64];   // 16384 B per-wave P, XOR-swizzled

    // waves 0,1 -> tile A; waves 2,3 -> tile B; shared K/V staging stream
    const int qw = ((w < 2) ? A * 64 : Bq * 64) + (w & 1) * 32;
    unsigned short* Plw = Pl + w * 32 * 64;
    const int pxor = (cl & 7) << 1;    // per-row XOR key on 8-short granules

    const float SCL = 0.18033688f;   // (1/8) * log2(e), folded into Q

    // Q fragments from fp32 global (once per block), pre-scaled by SCL
    bf16x8 qf[2][2];
#pragma unroll
    for (int m = 0; m < 2; ++m)
#pragma unroll
        for (int h = 0; h < 2; ++h) {
            const float* src = Qh + (size_t)(qw + m * 16 + cl) * DHEAD + h * 32 + quad * 8;
            float4 a = *(const float4*)src;
            float4 b = *(const float4*)(src + 4);
            uint4 u;
            u.x = pkbf(a.y * SCL, a.x * SCL); u.y = pkbf(a.w * SCL, a.z * SCL);
            u.z = pkbf(b.y * SCL, b.x * SCL); u.w = pkbf(b.w * SCL, b.z * SCL);
            qf[m][h] = __builtin_bit_cast(bf16x8, u);
        }

    f32x4 o[2][4];
#pragma unroll
    for (int m = 0; m < 2; ++m)
#pragma unroll
        for (int d = 0; d < 4; ++d) o[m][d] = (f32x4){0.f, 0.f, 0.f, 0.f};
    float ls[2] = {0.f, 0.f};

    // staging: 256 threads x 2 uint4 per tensor (tile = 512 uint4)
    const int p1 = tid + 256;
    const int srow0 = tid >> 3, sg0 = tid & 7;
    const int srow1 = p1 >> 3,  sg1 = p1 & 7;
    const int lo0 = swz(srow0, sg0), lo1 = swz(srow1, sg1);
    const size_t kS0 = (size_t)srow0 * DHEAD + sg0 * 8, kS1 = (size_t)srow1 * DHEAD + sg1 * 8;
    const size_t vS0 = (size_t)srow0 * SLEN + sg0 * 8,  vS1 = (size_t)srow1 * SLEN + sg1 * 8;

    const int ntiles = Bq + 1;
    uint4 kr0 = *(const uint4*)(Kh + kS0), kr1 = *(const uint4*)(Kh + kS1);
    uint4 vr0 = *(const uint4*)(Vth + vS0), vr1 = *(const uint4*)(Vth + vS1);

    for (int t = 0; t < ntiles; ++t) {
        const int k0 = t * 64;
        __syncthreads();                      // prior tile's readers done
        *(uint4*)(Kl + lo0) = kr0; *(uint4*)(Kl + lo1) = kr1;
        *(uint4*)(Vt + lo0) = vr0; *(uint4*)(Vt + lo1) = vr1;
        __syncthreads();
        if (t + 1 < ntiles) {                 // prefetch next tile into regs
            const size_t ko = (size_t)(k0 + 64) * DHEAD;
            kr0 = *(const uint4*)(Kh + kS0 + ko);
            kr1 = *(const uint4*)(Kh + kS1 + ko);
            vr0 = *(const uint4*)(Vth + vS0 + (k0 + 64));
            vr1 = *(const uint4*)(Vth + vS1 + (k0 + 64));
        }
        if (k0 > qw + 31) continue;           // wave-uniform; barriers are at loop top
        const bool partial = (k0 + 63 > qw);

        // S^T = K Q^T ; exp ; packed P^T write (swizzled 8B granule)
#pragma unroll
        for (int kk = 0; kk < 4; ++kk) {
            bf16x8 kb0 = __builtin_bit_cast(bf16x8, *(const uint4*)(Kl + swz(kk * 16 + cl, quad)));
            bf16x8 kb1 = __builtin_bit_cast(bf16x8, *(const uint4*)(Kl + swz(kk * 16 + cl, 4 + quad)));
            const int krel = kk * 16 + quad * 4;
#pragma unroll
            for (int qq = 0; qq < 2; ++qq) {
                f32x4 s = (f32x4){0.f, 0.f, 0.f, 0.f};
                s = __builtin_amdgcn_mfma_f32_16x16x32_bf16(kb0, qf[qq][0], s, 0, 0, 0);
                s = __builtin_amdgcn_mfma_f32_16x16x32_bf16(kb1, qf[qq][1], s, 0, 0, 0);
                float p0, p1v, p2, p3;
                if (partial) {
                    const int qrel = qw - k0 + qq * 16 + cl;
                    p0 = (krel + 0 <= qrel) ? __builtin_amdgcn_exp2f(s[0]) : 0.f;
                    p1v = (krel + 1 <= qrel) ? __builtin_amdgcn_exp2f(s[1]) : 0.f;
                    p2 = (krel + 2 <= qrel) ? __builtin_amdgcn_exp2f(s[2]) : 0.f;
                    p3 = (krel + 3 <= qrel) ? __builtin_amdgcn_exp2f(s[3]) : 0.f;
                } else {
                    p0 = __builtin_amdgcn_exp2f(s[0]);
                    p1v = __builtin_amdgcn_exp2f(s[1]);
                    p2 = __builtin_amdgcn_exp2f(s[2]);
                    p3 = __builtin_amdgcn_exp2f(s[3]);
                }
                ls[qq] += (p0 + p1v) + (p2 + p3);
                uint2 pw;
                asm("v_cvt_pk_bf16_f32 %0, %1, %2" : "=v"(pw.x) : "v"(p0), "v"(p1v));
                asm("v_cvt_pk_bf16_f32 %0, %1, %2" : "=v"(pw.y) : "v"(p2), "v"(p3));
                // row = qq*16+cl, col8 = kk*4+quad, swizzled col8^pxor
                *(uint2*)(Plw + (qq * 16 + cl) * 64 + (((kk * 4 + quad) ^ pxor) << 2)) = pw;
            }
        }

        // P A-frags (swizzled read; col8 = h*8+quad*2 even -> 16B align kept)
        bf16x8 pa[2][2];
#pragma unroll
        for (int m = 0; m < 2; ++m)
#pragma unroll
            for (int h = 0; h < 2; ++h)
                pa[m][h] = __builtin_bit_cast(bf16x8,
                    *(const uint4*)(Plw + (m * 16 + cl) * 64 + (((h * 8 + quad * 2) ^ pxor) << 2)));
#pragma unroll
        for (int dd = 0; dd < 4; ++dd) {
            bf16x8 vb0 = __builtin_bit_cast(bf16x8, *(const uint4*)(Vt + swz(dd * 16 + cl, quad)));
            bf16x8 vb1 = __builtin_bit_cast(bf16x8, *(const uint4*)(Vt + swz(dd * 16 + cl, 4 + quad)));
#pragma unroll
            for (int m = 0; m < 2; ++m) {
                o[m][dd] = __builtin_amdgcn_mfma_f32_16x16x32_bf16(pa[m][0], vb0, o[m][dd], 0, 0, 0);
                o[m][dd] = __builtin_amdgcn_mfma_f32_16x16x32_bf16(pa[m][1], vb1, o[m][dd], 0, 0, 0);
            }
        }
    }

    // row-sum: reduce across the 4 quads holding the same q (=cl)
#pragma unroll
    for (int qq = 0; qq < 2; ++qq) {
        float v = ls[qq];
        v += __shfl_xor(v, 16);
        v += __shfl_xor(v, 32);
        ls[qq] = v;
    }

    // normalize + store: O row q = qw + m*16 + quad*4 + r, col = dd*16 + cl
#pragma unroll
    for (int m = 0; m < 2; ++m)
#pragma unroll
        for (int r = 0; r < 4; ++r) {
            const float inv = 1.0f / __shfl(ls[m], quad * 4 + r);
#pragma unroll
            for (int dd = 0; dd < 4; ++dd)
                Oh[(size_t)(qw + m * 16 + quad * 4 + r) * DHEAD + dd * 16 + cl] = o[m][dd][r] * inv;
        }
}

extern "C" void kernel_launch(void* const* d_in, const int* in_sizes, int n_in,
                              void* d_out, int out_size, void* d_ws, size_t ws_size,
                              hipStream_t stream) {
    const float* Q = (const float*)d_in[0];
    const float* K = (const float*)d_in[1];
    const float* V = (const float*)d_in[2];
    float*       O = (float*)d_out;

    unsigned short* Kbf  = (unsigned short*)d_ws;
    unsigned short* Vtbf = Kbf + NELEM;

    convert_prep<<<dim3(4096 + 512), dim3(256), 0, stream>>>(K, V, Kbf, Vtbf);
    sdpa_mfma<<<dim3(1024), dim3(256), 0, stream>>>(Q, Kbf, Vtbf, O);
}

// Round 11
// 194.847 us; speedup vs baseline: 1.9582x; 1.9582x over previous
//
#include <hip/hip_runtime.h>
#include <stdint.h>

// Causal SDPA B=4,H=16,S=2048,D=64 fp32. Flash-MFMA bf16, round 15.
// EXACT v8 structure (75.0us sdpa, round 4: pair-blocks (A,31-A),
// head=n&63 -> same-XCD L2 stream, 2-barrier staging, x32 PV via P-LDS,
// cvt_pk pack, scale folded into Q) + ONE variable: P-buffer XOR-swizzle
// replacing PADP padding.
//   P dense [32][64], granule col4' = col4 ^ ((cl&7)<<1) (4-short
//   granules, even XOR -> 16B alignment of b128 reads preserved).
//   Correctness-proven r13 (passed); conflicts 3.24M->2.16M measured.
//   LDS 34816 -> 32768. launch_bounds stays (256,4): r13 proved (256,5)
//   register-starves (VGPR 48, +550MB spill traffic); occupancy is
//   register-capped at 4 waves/EU.
// v14 post-mortem: strip-interleave failed correctness (absmax 20.5 =
// ls/O mismatch signature); bug un-located by inspection -> shelved.

#define SLEN 2048
#define DHEAD 64
#define NHEADS 64
#define NELEM (SLEN * DHEAD * NHEADS)   // 8388608 per tensor

typedef short bf16x8 __attribute__((ext_vector_type(8)));
typedef float f32x4 __attribute__((ext_vector_type(4)));

__device__ __forceinline__ uint32_t pkbf(float hi, float lo) {
    uint32_t a = __builtin_bit_cast(uint32_t, lo) + 0x8000u;
    uint32_t b = __builtin_bit_cast(uint32_t, hi) + 0x8000u;
    return __builtin_amdgcn_perm(b, a, 0x07060302u);
}
__device__ __forceinline__ unsigned short f2bf(float f) {
    return (unsigned short)((__builtin_bit_cast(uint32_t, f) + 0x8000u) >> 16);
}
__device__ __forceinline__ int swz(int row, int g) {  // offset in shorts, 64x64 tile
    return row * 64 + ((g ^ (row & 7)) << 3);
}

// ---------------- pass 1: K straight, V transposed (identical to round 0) ----------------
__global__ __launch_bounds__(256)
void convert_prep(const float* __restrict__ K, const float* __restrict__ V,
                  unsigned short* __restrict__ Kb, unsigned short* __restrict__ Vtb) {
    __shared__ unsigned short Lt[64 * 264];
    const int b = blockIdx.x, t = threadIdx.x;
    if (b < 4096) {
        const int off = (b * 256 + t) * 8;
        float4 a = *(const float4*)(K + off);
        float4 c = *(const float4*)(K + off + 4);
        uint4 o;
        o.x = pkbf(a.y, a.x); o.y = pkbf(a.w, a.z);
        o.z = pkbf(c.y, c.x); o.w = pkbf(c.w, c.z);
        *(uint4*)(Kb + off) = o;
    } else {
        const int vb2 = b - 4096;
        const int head = vb2 >> 3, kblk = vb2 & 7;
        const float* Vh = V + (size_t)head * (SLEN * DHEAD) + kblk * 256 * DHEAD;
        unsigned short* Vo = Vtb + (size_t)head * (SLEN * DHEAD) + kblk * 256;
#pragma unroll
        for (int i = 0; i < 16; ++i) {
            int idx = t + 256 * i;
            int key = idx >> 4, d4 = idx & 15;
            float4 v = *(const float4*)(Vh + key * DHEAD + d4 * 4);
            Lt[(d4 * 4 + 0) * 264 + key] = f2bf(v.x);
            Lt[(d4 * 4 + 1) * 264 + key] = f2bf(v.y);
            Lt[(d4 * 4 + 2) * 264 + key] = f2bf(v.z);
            Lt[(d4 * 4 + 3) * 264 + key] = f2bf(v.w);
        }
        __syncthreads();
#pragma unroll
        for (int jj = 0; jj < 8; ++jj) {
            int idx = t + 256 * jj;
            int d = idx >> 5, k8 = idx & 31;
            *(uint4*)(Vo + (size_t)d * SLEN + k8 * 8) = *(const uint4*)(Lt + d * 264 + k8 * 8);
        }
    }
}

// ---------------- pass 2: flash attention, balanced pair-blocks ----------------
__global__ __launch_bounds__(256, 4)
void sdpa_mfma(const float* __restrict__ Qf, const unsigned short* __restrict__ Kb,
               const unsigned short* __restrict__ Vtb, float* __restrict__ Og) {
    const int n = blockIdx.x;
    const int j = n >> 8, c = n & 255;
    const int head = c & 63;           // head%8 == n%8 -> same-XCD L2 stream
    const int A  = (c >> 6) + 4 * j;   // 0..15
    const int Bq = 31 - A;             // 16..31

    const size_t hb = (size_t)head * SLEN * DHEAD;
    const float* Qh = Qf + hb;
    const unsigned short* Kh  = Kb + hb;
    const unsigned short* Vth = Vtb + hb;   // [d][2048]
    float* Oh = Og + hb;

    const int tid  = threadIdx.x;
    const int w    = tid >> 6, lane = tid & 63;
    const int cl   = lane & 15, quad = lane >> 4;

    __shared__ unsigned short Kl[64 * 64];       //  8192 B swizzled [key][d]
    __shared__ unsigned short Vt[64 * 64];       //  8192 B swizzled [d][key]
    __shared__ unsigned short Pl[4 * 32 * 64];   // 16384 B per-wave P, XOR-swizzled

    // waves 0,1 -> tile A; waves 2,3 -> tile B; shared K/V staging stream
    const int qw = ((w < 2) ? A * 64 : Bq * 64) + (w & 1) * 32;
    unsigned short* Plw = Pl + w * 32 * 64;
    const int pxor = (cl & 7) << 1;    // per-row XOR key on 4-short granules

    const float SCL = 0.18033688f;   // (1/8) * log2(e), folded into Q

    // Q fragments from fp32 global (once per block), pre-scaled by SCL
    bf16x8 qf[2][2];
#pragma unroll
    for (int m = 0; m < 2; ++m)
#pragma unroll
        for (int h = 0; h < 2; ++h) {
            const float* src = Qh + (size_t)(qw + m * 16 + cl) * DHEAD + h * 32 + quad * 8;
            float4 a = *(const float4*)src;
            float4 b = *(const float4*)(src + 4);
            uint4 u;
            u.x = pkbf(a.y * SCL, a.x * SCL); u.y = pkbf(a.w * SCL, a.z * SCL);
            u.z = pkbf(b.y * SCL, b.x * SCL); u.w = pkbf(b.w * SCL, b.z * SCL);
            qf[m][h] = __builtin_bit_cast(bf16x8, u);
        }

    f32x4 o[2][4];
#pragma unroll
    for (int m = 0; m < 2; ++m)
#pragma unroll
        for (int d = 0; d < 4; ++d) o[m][d] = (f32x4){0.f, 0.f, 0.f, 0.f};
    float ls[2] = {0.f, 0.f};

    // staging: 256 threads x 2 uint4 per tensor (tile = 512 uint4)
    const int p1 = tid + 256;
    const int srow0 = tid >> 3, sg0 = tid & 7;
    const int srow1 = p1 >> 3,  sg1 = p1 & 7;
    const int lo0 = swz(srow0, sg0), lo1 = swz(srow1, sg1);
    const size_t kS0 = (size_t)srow0 * DHEAD + sg0 * 8, kS1 = (size_t)srow1 * DHEAD + sg1 * 8;
    const size_t vS0 = (size_t)srow0 * SLEN + sg0 * 8,  vS1 = (size_t)srow1 * SLEN + sg1 * 8;

    const int ntiles = Bq + 1;
    uint4 kr0 = *(const uint4*)(Kh + kS0), kr1 = *(const uint4*)(Kh + kS1);
    uint4 vr0 = *(const uint4*)(Vth + vS0), vr1 = *(const uint4*)(Vth + vS1);

    for (int t = 0; t < ntiles; ++t) {
        const int k0 = t * 64;
        __syncthreads();                      // prior tile's readers done
        *(uint4*)(Kl + lo0) = kr0; *(uint4*)(Kl + lo1) = kr1;
        *(uint4*)(Vt + lo0) = vr0; *(uint4*)(Vt + lo1) = vr1;
        __syncthreads();
        if (t + 1 < ntiles) {                 // prefetch next tile into regs
            const size_t ko = (size_t)(k0 + 64) * DHEAD;
            kr0 = *(const uint4*)(Kh + kS0 + ko);
            kr1 = *(const uint4*)(Kh + kS1 + ko);
            vr0 = *(const uint4*)(Vth + vS0 + (k0 + 64));
            vr1 = *(const uint4*)(Vth + vS1 + (k0 + 64));
        }
        if (k0 > qw + 31) continue;           // wave-uniform; barriers are at loop top
        const bool partial = (k0 + 63 > qw);

        // S^T = K Q^T ; exp ; packed P^T write (XOR-swizzled 8B granule)
#pragma unroll
        for (int kk = 0; kk < 4; ++kk) {
            bf16x8 kb0 = __builtin_bit_cast(bf16x8, *(const uint4*)(Kl + swz(kk * 16 + cl, quad)));
            bf16x8 kb1 = __builtin_bit_cast(bf16x8, *(const uint4*)(Kl + swz(kk * 16 + cl, 4 + quad)));
            const int krel = kk * 16 + quad * 4;
#pragma unroll
            for (int qq = 0; qq < 2; ++qq) {
                f32x4 s = (f32x4){0.f, 0.f, 0.f, 0.f};
                s = __builtin_amdgcn_mfma_f32_16x16x32_bf16(kb0, qf[qq][0], s, 0, 0, 0);
                s = __builtin_amdgcn_mfma_f32_16x16x32_bf16(kb1, qf[qq][1], s, 0, 0, 0);
                float p0, p1v, p2, p3;
                if (partial) {
                    const int qrel = qw - k0 + qq * 16 + cl;
                    p0 = (krel + 0 <= qrel) ? __builtin_amdgcn_exp2f(s[0]) : 0.f;
                    p1v = (krel + 1 <= qrel) ? __builtin_amdgcn_exp2f(s[1]) : 0.f;
                    p2 = (krel + 2 <= qrel) ? __builtin_amdgcn_exp2f(s[2]) : 0.f;
                    p3 = (krel + 3 <= qrel) ? __builtin_amdgcn_exp2f(s[3]) : 0.f;
                } else {
                    p0 = __builtin_amdgcn_exp2f(s[0]);
                    p1v = __builtin_amdgcn_exp2f(s[1]);
                    p2 = __builtin_amdgcn_exp2f(s[2]);
                    p3 = __builtin_amdgcn_exp2f(s[3]);
                }
                ls[qq] += (p0 + p1v) + (p2 + p3);
                uint2 pw;
                asm("v_cvt_pk_bf16_f32 %0, %1, %2" : "=v"(pw.x) : "v"(p0), "v"(p1v));
                asm("v_cvt_pk_bf16_f32 %0, %1, %2" : "=v"(pw.y) : "v"(p2), "v"(p3));
                // row = qq*16+cl, granule = kk*4+quad, physical = granule^pxor
                *(uint2*)(Plw + (qq * 16 + cl) * 64 + (((kk * 4 + quad) ^ pxor) << 2)) = pw;
            }
        }

        // P A-frags (swizzled read; logical granule h*8+quad*2 even -> 16B align kept)
        bf16x8 pa[2][2];
#pragma unroll
        for (int m = 0; m < 2; ++m)
#pragma unroll
            for (int h = 0; h < 2; ++h)
                pa[m][h] = __builtin_bit_cast(bf16x8,
                    *(const uint4*)(Plw + (m * 16 + cl) * 64 + (((h * 8 + quad * 2) ^ pxor) << 2)));
#pragma unroll
        for (int dd = 0; dd < 4; ++dd) {
            bf16x8 vb0 = __builtin_bit_cast(bf16x8, *(const uint4*)(Vt + swz(dd * 16 + cl, quad)));
            bf16x8 vb1 = __builtin_bit_cast(bf16x8, *(const uint4*)(Vt + swz(dd * 16 + cl, 4 + quad)));
#pragma unroll
            for (int m = 0; m < 2; ++m) {
                o[m][dd] = __builtin_amdgcn_mfma_f32_16x16x32_bf16(pa[m][0], vb0, o[m][dd], 0, 0, 0);
                o[m][dd] = __builtin_amdgcn_mfma_f32_16x16x32_bf16(pa[m][1], vb1, o[m][dd], 0, 0, 0);
            }
        }
    }

    // row-sum: reduce across the 4 quads holding the same q (=cl)
#pragma unroll
    for (int qq = 0; qq < 2; ++qq) {
        float v = ls[qq];
        v += __shfl_xor(v, 16);
        v += __shfl_xor(v, 32);
        ls[qq] = v;
    }

    // normalize + store: O row q = qw + m*16 + quad*4 + r, col = dd*16 + cl
#pragma unroll
    for (int m = 0; m < 2; ++m)
#pragma unroll
        for (int r = 0; r < 4; ++r) {
            const float inv = 1.0f / __shfl(ls[m], quad * 4 + r);
#pragma unroll
            for (int dd = 0; dd < 4; ++dd)
                Oh[(size_t)(qw + m * 16 + quad * 4 + r) * DHEAD + dd * 16 + cl] = o[m][dd][r] * inv;
        }
}

extern "C" void kernel_launch(void* const* d_in, const int* in_sizes, int n_in,
                              void* d_out, int out_size, void* d_ws, size_t ws_size,
                              hipStream_t stream) {
    const float* Q = (const float*)d_in[0];
    const float* K = (const float*)d_in[1];
    const float* V = (const float*)d_in[2];
    float*       O = (float*)d_out;

    unsigned short* Kbf  = (unsigned short*)d_ws;
    unsigned short* Vtbf = Kbf + NELEM;

    convert_prep<<<dim3(4096 + 512), dim3(256), 0, stream>>>(K, V, Kbf, Vtbf);
    sdpa_mfma<<<dim3(1024), dim3(256), 0, stream>>>(Q, Kbf, Vtbf, O);
}

// Round 12
// 191.130 us; speedup vs baseline: 1.9963x; 1.0194x over previous
//
#include <hip/hip_runtime.h>
#include <stdint.h>

// Causal SDPA B=4,H=16,S=2048,D=64 fp32. Flash-MFMA bf16, round 16.
// COMPOSITION of two individually-proven components:
//   v10's 1-barrier-per-tile double-buffered staging (correctness proven;
//     its only failure was LDS 51200 -> 3 blocks/CU occupancy loss), and
//   v9's x16-PV register-P body (correctness proven; P-LDS eliminated;
//     only +5.6us standalone) -> LDS = 2x(8K+8K) = 32768 -> 4 blocks/CU.
// Net: barrier count halves AT CONSTANT OCCUPANCY. v10 evidence: 1-barrier
// beat pure occupancy-scaling by ~25% (94.6 vs ~125 predicted) -> sync
// overhead ~15-20us/kernel; this captures it without paying occupancy.
// v15 post-mortem: P XOR-swizzle removed 1.1M conflicts but +5.5us ->
// P conflicts were latency-hidden; conflict-chasing dead. Reverted.
// Ledger: wall ~ 1/waves (v10,v13); reg-capped 4 waves/EU, (256,5) spills
// (v13); head==n mod 8 -> XCD-local L2 (v12); scale-in-Q + cvt_pk (v8).

#define SLEN 2048
#define DHEAD 64
#define NHEADS 64
#define NELEM (SLEN * DHEAD * NHEADS)   // 8388608 per tensor

typedef short bf16x8 __attribute__((ext_vector_type(8)));
typedef short bf16x4 __attribute__((ext_vector_type(4)));
typedef float f32x4 __attribute__((ext_vector_type(4)));

__device__ __forceinline__ uint32_t pkbf(float hi, float lo) {
    uint32_t a = __builtin_bit_cast(uint32_t, lo) + 0x8000u;
    uint32_t b = __builtin_bit_cast(uint32_t, hi) + 0x8000u;
    return __builtin_amdgcn_perm(b, a, 0x07060302u);
}
__device__ __forceinline__ unsigned short f2bf(float f) {
    return (unsigned short)((__builtin_bit_cast(uint32_t, f) + 0x8000u) >> 16);
}
__device__ __forceinline__ int swz(int row, int g) {  // offset in shorts, 64x64 tile
    return row * 64 + ((g ^ (row & 7)) << 3);
}

__device__ __forceinline__ f32x4 mfma16(bf16x4 a, bf16x4 b, f32x4 c) {
#if __has_builtin(__builtin_amdgcn_mfma_f32_16x16x16bf16_1k)
    return __builtin_amdgcn_mfma_f32_16x16x16bf16_1k(a, b, c, 0, 0, 0);
#else
    asm("v_mfma_f32_16x16x16_bf16 %0, %1, %2, %0" : "+v"(c) : "v"(a), "v"(b));
    return c;
#endif
}

// ---------------- pass 1: K straight, V transposed (identical to round 0) ----------------
__global__ __launch_bounds__(256)
void convert_prep(const float* __restrict__ K, const float* __restrict__ V,
                  unsigned short* __restrict__ Kb, unsigned short* __restrict__ Vtb) {
    __shared__ unsigned short Lt[64 * 264];
    const int b = blockIdx.x, t = threadIdx.x;
    if (b < 4096) {
        const int off = (b * 256 + t) * 8;
        float4 a = *(const float4*)(K + off);
        float4 c = *(const float4*)(K + off + 4);
        uint4 o;
        o.x = pkbf(a.y, a.x); o.y = pkbf(a.w, a.z);
        o.z = pkbf(c.y, c.x); o.w = pkbf(c.w, c.z);
        *(uint4*)(Kb + off) = o;
    } else {
        const int vb2 = b - 4096;
        const int head = vb2 >> 3, kblk = vb2 & 7;
        const float* Vh = V + (size_t)head * (SLEN * DHEAD) + kblk * 256 * DHEAD;
        unsigned short* Vo = Vtb + (size_t)head * (SLEN * DHEAD) + kblk * 256;
#pragma unroll
        for (int i = 0; i < 16; ++i) {
            int idx = t + 256 * i;
            int key = idx >> 4, d4 = idx & 15;
            float4 v = *(const float4*)(Vh + key * DHEAD + d4 * 4);
            Lt[(d4 * 4 + 0) * 264 + key] = f2bf(v.x);
            Lt[(d4 * 4 + 1) * 264 + key] = f2bf(v.y);
            Lt[(d4 * 4 + 2) * 264 + key] = f2bf(v.z);
            Lt[(d4 * 4 + 3) * 264 + key] = f2bf(v.w);
        }
        __syncthreads();
#pragma unroll
        for (int jj = 0; jj < 8; ++jj) {
            int idx = t + 256 * jj;
            int d = idx >> 5, k8 = idx & 31;
            *(uint4*)(Vo + (size_t)d * SLEN + k8 * 8) = *(const uint4*)(Lt + d * 264 + k8 * 8);
        }
    }
}

// ---------------- pass 2: flash attention, dbuf 1-barrier + register-P ----------------
__global__ __launch_bounds__(256, 4)
void sdpa_mfma(const float* __restrict__ Qf, const unsigned short* __restrict__ Kb,
               const unsigned short* __restrict__ Vtb, float* __restrict__ Og) {
    const int n = blockIdx.x;
    const int j = n >> 8, c = n & 255;
    const int head = c & 63;           // head%8 == n%8 -> same-XCD L2 stream
    const int A  = (c >> 6) + 4 * j;   // 0..15
    const int Bq = 31 - A;             // 16..31

    const size_t hb = (size_t)head * SLEN * DHEAD;
    const float* Qh = Qf + hb;
    const unsigned short* Kh  = Kb + hb;
    const unsigned short* Vth = Vtb + hb;   // [d][2048]
    float* Oh = Og + hb;

    const int tid  = threadIdx.x;
    const int w    = tid >> 6, lane = tid & 63;
    const int cl   = lane & 15, quad = lane >> 4;

    __shared__ unsigned short Kl[2][64 * 64];  // 16384 B swizzled [key][d], dbuf
    __shared__ unsigned short Vt[2][64 * 64];  // 16384 B swizzled [d][key], dbuf

    // waves 0,1 -> tile A; waves 2,3 -> tile B; shared K/V staging stream
    const int qw = ((w < 2) ? A * 64 : Bq * 64) + (w & 1) * 32;

    const float SCL = 0.18033688f;   // (1/8) * log2(e), folded into Q

    // Q fragments from fp32 global (once per block), pre-scaled by SCL
    bf16x8 qf[2][2];
#pragma unroll
    for (int m = 0; m < 2; ++m)
#pragma unroll
        for (int h = 0; h < 2; ++h) {
            const float* src = Qh + (size_t)(qw + m * 16 + cl) * DHEAD + h * 32 + quad * 8;
            float4 a = *(const float4*)src;
            float4 b = *(const float4*)(src + 4);
            uint4 u;
            u.x = pkbf(a.y * SCL, a.x * SCL); u.y = pkbf(a.w * SCL, a.z * SCL);
            u.z = pkbf(b.y * SCL, b.x * SCL); u.w = pkbf(b.w * SCL, b.z * SCL);
            qf[m][h] = __builtin_bit_cast(bf16x8, u);
        }

    f32x4 o[2][4];
#pragma unroll
    for (int m = 0; m < 2; ++m)
#pragma unroll
        for (int d = 0; d < 4; ++d) o[m][d] = (f32x4){0.f, 0.f, 0.f, 0.f};
    float ls[2] = {0.f, 0.f};

    // staging: 256 threads x 2 uint4 per tensor (tile = 512 uint4)
    const int p1 = tid + 256;
    const int srow0 = tid >> 3, sg0 = tid & 7;
    const int srow1 = p1 >> 3,  sg1 = p1 & 7;
    const int lo0 = swz(srow0, sg0), lo1 = swz(srow1, sg1);
    const size_t kS0 = (size_t)srow0 * DHEAD + sg0 * 8, kS1 = (size_t)srow1 * DHEAD + sg1 * 8;
    const size_t vS0 = (size_t)srow0 * SLEN + sg0 * 8,  vS1 = (size_t)srow1 * SLEN + sg1 * 8;

    const int ntiles = Bq + 1;
    uint4 kr0 = *(const uint4*)(Kh + kS0), kr1 = *(const uint4*)(Kh + kS1);
    uint4 vr0 = *(const uint4*)(Vth + vS0), vr1 = *(const uint4*)(Vth + vS1);

    for (int t = 0; t < ntiles; ++t) {
        const int k0 = t * 64;
        unsigned short* Kc = Kl[t & 1];
        unsigned short* Vc = Vt[t & 1];
        // write tile t into buf[t&1]: race-free with ONE barrier/tile (v10):
        // any wave here passed barrier(t-1), hence (program order) finished
        // its compute(t-2) = the last read of this buffer.
        *(uint4*)(Kc + lo0) = kr0; *(uint4*)(Kc + lo1) = kr1;
        *(uint4*)(Vc + lo0) = vr0; *(uint4*)(Vc + lo1) = vr1;
        __syncthreads();
        if (t + 1 < ntiles) {                 // prefetch next tile; drains at
            const size_t ko = (size_t)(k0 + 64) * DHEAD;   // next loop-top write
            kr0 = *(const uint4*)(Kh + kS0 + ko);
            kr1 = *(const uint4*)(Kh + kS1 + ko);
            vr0 = *(const uint4*)(Vth + vS0 + (k0 + 64));
            vr1 = *(const uint4*)(Vth + vS1 + (k0 + 64));
        }
        if (k0 > qw + 31) continue;           // skips compute only; barrier above
        const bool partial = (k0 + 63 > qw);

        // per 16-key chunk: S^T = K Q^T ; exp ; cvt_pk -> x16 A-frag ; O += P V
#pragma unroll
        for (int kk = 0; kk < 4; ++kk) {
            bf16x8 kb0 = __builtin_bit_cast(bf16x8, *(const uint4*)(Kc + swz(kk * 16 + cl, quad)));
            bf16x8 kb1 = __builtin_bit_cast(bf16x8, *(const uint4*)(Kc + swz(kk * 16 + cl, 4 + quad)));
            const int krel = kk * 16 + quad * 4;
            bf16x4 paf[2];
#pragma unroll
            for (int qq = 0; qq < 2; ++qq) {
                f32x4 s = (f32x4){0.f, 0.f, 0.f, 0.f};
                s = __builtin_amdgcn_mfma_f32_16x16x32_bf16(kb0, qf[qq][0], s, 0, 0, 0);
                s = __builtin_amdgcn_mfma_f32_16x16x32_bf16(kb1, qf[qq][1], s, 0, 0, 0);
                float p0, p1v, p2, p3;
                if (partial) {
                    const int qrel = qw - k0 + qq * 16 + cl;
                    p0 = (krel + 0 <= qrel) ? __builtin_amdgcn_exp2f(s[0]) : 0.f;
                    p1v = (krel + 1 <= qrel) ? __builtin_amdgcn_exp2f(s[1]) : 0.f;
                    p2 = (krel + 2 <= qrel) ? __builtin_amdgcn_exp2f(s[2]) : 0.f;
                    p3 = (krel + 3 <= qrel) ? __builtin_amdgcn_exp2f(s[3]) : 0.f;
                } else {
                    p0 = __builtin_amdgcn_exp2f(s[0]);
                    p1v = __builtin_amdgcn_exp2f(s[1]);
                    p2 = __builtin_amdgcn_exp2f(s[2]);
                    p3 = __builtin_amdgcn_exp2f(s[3]);
                }
                ls[qq] += (p0 + p1v) + (p2 + p3);
                uint2 pw;
                asm("v_cvt_pk_bf16_f32 %0, %1, %2" : "=v"(pw.x) : "v"(p0), "v"(p1v));
                asm("v_cvt_pk_bf16_f32 %0, %1, %2" : "=v"(pw.y) : "v"(p2), "v"(p3));
                paf[qq] = __builtin_bit_cast(bf16x4, pw);
            }
            // PV for this 16-key chunk: B-frag = V^T[d = dd*16+cl][keys krel..krel+3]
#pragma unroll
            for (int dd = 0; dd < 4; ++dd) {
                const int vrow = dd * 16 + cl;
                const unsigned short* vp = Vc + vrow * 64
                    + ((((2 * kk + (quad >> 1)) ^ (cl & 7)) << 3) + (quad & 1) * 4);
                bf16x4 vb = __builtin_bit_cast(bf16x4, *(const uint2*)vp);
                o[0][dd] = mfma16(paf[0], vb, o[0][dd]);
                o[1][dd] = mfma16(paf[1], vb, o[1][dd]);
            }
        }
    }

    // row-sum: reduce across the 4 quads holding the same q (=cl)
#pragma unroll
    for (int qq = 0; qq < 2; ++qq) {
        float v = ls[qq];
        v += __shfl_xor(v, 16);
        v += __shfl_xor(v, 32);
        ls[qq] = v;
    }

    // normalize + store: O row q = qw + m*16 + quad*4 + r, col = dd*16 + cl
#pragma unroll
    for (int m = 0; m < 2; ++m)
#pragma unroll
        for (int r = 0; r < 4; ++r) {
            const float inv = 1.0f / __shfl(ls[m], quad * 4 + r);
#pragma unroll
            for (int dd = 0; dd < 4; ++dd)
                Oh[(size_t)(qw + m * 16 + quad * 4 + r) * DHEAD + dd * 16 + cl] = o[m][dd][r] * inv;
        }
}

extern "C" void kernel_launch(void* const* d_in, const int* in_sizes, int n_in,
                              void* d_out, int out_size, void* d_ws, size_t ws_size,
                              hipStream_t stream) {
    const float* Q = (const float*)d_in[0];
    const float* K = (const float*)d_in[1];
    const float* V = (const float*)d_in[2];
    float*       O = (float*)d_out;

    unsigned short* Kbf  = (unsigned short*)d_ws;
    unsigned short* Vtbf = Kbf + NELEM;

    convert_prep<<<dim3(4096 + 512), dim3(256), 0, stream>>>(K, V, Kbf, Vtbf);
    sdpa_mfma<<<dim3(1024), dim3(256), 0, stream>>>(Q, Kbf, Vtbf, O);
}